// Round 1
// baseline (17.228 us; speedup 1.0000x reference)
//
#include <hip/hip_runtime.h>

#define NT 512

// Fused policy net: conv1(1x3)+leaky -> conv2(1x48)+leaky -> fc(50->10) -> softmax
// Single workgroup; stages separated by barriers; all intermediates in LDS.
__global__ __launch_bounds__(NT) void policy_35742717837418_kernel(
    const float* __restrict__ s,    // [4][25][50]
    const float* __restrict__ w1,   // [8][4][1][3]
    const float* __restrict__ b1,   // [8]
    const float* __restrict__ w2,   // [2][8][1][48]
    const float* __restrict__ b2,   // [2]
    const float* __restrict__ wf,   // [10][50]
    const float* __restrict__ bf,   // [10]
    float* __restrict__ out)        // [10]
{
    __shared__ float sm_s[4 * 25 * 50];    // 5000 floats = 20 KB
    __shared__ float sm_x1[8 * 25 * 48];   // 9600 floats = 38.4 KB
    __shared__ float sm_w1[96];
    __shared__ float sm_b1[8];
    __shared__ float sm_w2[768];
    __shared__ float sm_b2[2];
    __shared__ float sm_x2[50];
    __shared__ float sm_logits[10];

    const int tid = threadIdx.x;

    // ---- Stage inputs into LDS (coalesced) ----
    for (int i = tid; i < 5000; i += NT) sm_s[i] = s[i];
    for (int i = tid; i < 768;  i += NT) sm_w2[i] = w2[i];
    if (tid < 96) sm_w1[tid] = w1[tid];
    if (tid < 8)  sm_b1[tid] = b1[tid];
    if (tid < 2)  sm_b2[tid] = b2[tid];
    __syncthreads();

    // ---- conv1: [4,25,50] -> [8,25,48], kernel (1,3), + bias + leaky(0.01) ----
    for (int idx = tid; idx < 8 * 25 * 48; idx += NT) {
        const int co  = idx / (25 * 48);
        const int rem = idx - co * (25 * 48);
        const int h   = rem / 48;
        const int w   = rem - h * 48;
        float acc = sm_b1[co];
        #pragma unroll
        for (int ci = 0; ci < 4; ++ci) {
            const float* sp = &sm_s[ci * 1250 + h * 50 + w];
            const float* wp = &sm_w1[co * 12 + ci * 3];
            acc = fmaf(sp[0], wp[0], acc);
            acc = fmaf(sp[1], wp[1], acc);
            acc = fmaf(sp[2], wp[2], acc);
        }
        sm_x1[idx] = (acc >= 0.0f) ? acc : 0.01f * acc;
    }
    __syncthreads();

    // ---- conv2: [8,25,48] -> [2,25,1], kernel (1,48), + bias + leaky(0.01) ----
    // 8 lanes per output; 64 groups (first 50 active); shuffle-reduce in group.
    {
        const int g = tid >> 3;   // output index: co*25 + h
        const int l = tid & 7;
        float acc = 0.0f;
        if (g < 50) {
            const int co = g / 25;
            const int h  = g - co * 25;
            const float* x1row = &sm_x1[h * 48];          // + ci*1200
            const float* w2row = &sm_w2[co * 384];
            #pragma unroll
            for (int ci = 0; ci < 8; ++ci) {
                const float* xp = x1row + ci * 1200;
                const float* wp = w2row + ci * 48;
                for (int kw = l; kw < 48; kw += 8)
                    acc = fmaf(xp[kw], wp[kw], acc);
            }
        }
        // reduce across the 8-lane group (groups are wave-aligned: 8 | 64)
        acc += __shfl_xor(acc, 1);
        acc += __shfl_xor(acc, 2);
        acc += __shfl_xor(acc, 4);
        if (g < 50 && l == 0) {
            const int co = g / 25;
            const float v = acc + sm_b2[co];
            sm_x2[g] = (v >= 0.0f) ? v : 0.01f * v;
        }
    }
    __syncthreads();

    // ---- fc: logits[k] = wf[k,:] @ x2 + bf[k] ----
    if (tid < 10) {
        float acc = bf[tid];
        const float* wrow = &wf[tid * 50];
        #pragma unroll
        for (int j = 0; j < 50; ++j)
            acc = fmaf(wrow[j], sm_x2[j], acc);
        sm_logits[tid] = acc;
    }
    __syncthreads();

    // ---- softmax over 10 (serial on one thread; trivial) ----
    if (tid == 0) {
        float m = sm_logits[0];
        #pragma unroll
        for (int i = 1; i < 10; ++i) m = fmaxf(m, sm_logits[i]);
        float e[10];
        float sum = 0.0f;
        #pragma unroll
        for (int i = 0; i < 10; ++i) { e[i] = expf(sm_logits[i] - m); sum += e[i]; }
        const float inv = 1.0f / sum;
        #pragma unroll
        for (int i = 0; i < 10; ++i) out[i] = e[i] * inv;
    }
}

extern "C" void kernel_launch(void* const* d_in, const int* in_sizes, int n_in,
                              void* d_out, int out_size, void* d_ws, size_t ws_size,
                              hipStream_t stream) {
    const float* s  = (const float*)d_in[0];
    const float* w1 = (const float*)d_in[1];
    const float* b1 = (const float*)d_in[2];
    const float* w2 = (const float*)d_in[3];
    const float* b2 = (const float*)d_in[4];
    const float* wf = (const float*)d_in[5];
    const float* bf = (const float*)d_in[6];
    float* out = (float*)d_out;

    policy_35742717837418_kernel<<<1, NT, 0, stream>>>(s, w1, b1, w2, b2, wf, bf, out);
}